// Round 2
// baseline (1121.194 us; speedup 1.0000x reference)
//
#include <hip/hip_runtime.h>
#include <hip/hip_cooperative_groups.h>

namespace cg = cooperative_groups;

// Problem constants derived at launch from in_sizes:
// in[0]=x [B,TF,T], in[1]=gene_ids [T], in[2]=w_sub [TF,T], in[3]=b_sub [G],
// in[4]=edge_index [2,2E], in[5]=w_conv [1,2], in[6]=b_conv [2],
// in[7]=w_out [2G,3], in[8]=b_out [3]
// d_out = x_cat [B,G] ++ g [B,2G] ++ out [B,3]  (float32)

typedef float f32x4 __attribute__((ext_vector_type(4)));

// ==================== Cooperative mega-kernel: all stages, one launch ==========
// Phases separated by grid.sync():
//   P0: zero ws (acc|deg|s) + bias-init out_fin
//   P1: subnet dot + segment scatter into acc           (448 MB x-stream, HBM-bound)
//   P2: x_cat = relu(acc+b_sub) ; deg count
//   P3: edge scatter with on-the-fly GCN norm
//   P4: g = relu(w_conv*s+b_conv) ; out = g @ w_out + b_out  (wave-reduce + atomics)
__global__ __launch_bounds__(256, 4)
void k_mega(const float* __restrict__ x, const int* __restrict__ gene_ids,
            const float* __restrict__ w_sub, const float* __restrict__ b_sub,
            const int* __restrict__ ei, const float* __restrict__ w_conv,
            const float* __restrict__ b_conv, const float* __restrict__ w_out,
            const float* __restrict__ b_out,
            float* __restrict__ acc, float* __restrict__ deg, float* __restrict__ s,
            float* __restrict__ out_xcat, float* __restrict__ out_g,
            float* __restrict__ out_fin,
            int B, int TF, int T, int G, int E2) {
    cg::grid_group gg = cg::this_grid();
    const int tid = blockIdx.x * blockDim.x + threadIdx.x;
    const int nth = gridDim.x * blockDim.x;
    const int BG = B * G;

    // ---- P0: zero acc[BG] | deg[G] | s[BG] (contiguous in ws) + out_fin bias ----
    const int ztot = BG + G + BG;
    for (int i = tid; i < ztot; i += nth) acc[i] = 0.f;
    if (tid < B * 3) out_fin[tid] = b_out[tid % 3];
    gg.sync();

    // ---- P1: z[b,t-quad] = sum_tf x*w ; merge-adjacent-gene atomics into acc ----
    {
        const int NQ = T >> 2;                 // T % 4 == 0 for this problem
        const int njobs = B * NQ;              // b-major so waves read contiguous x
        const size_t strideV = (size_t)NQ;
        for (int job = tid; job < njobs; job += nth) {
            int b = job / NQ;
            int q = job - b * NQ;
            int t = q << 2;
            const f32x4* xp = (const f32x4*)(x + (size_t)b * TF * T + t);
            const f32x4* wp = (const f32x4*)(w_sub + t);
            f32x4 a = {0.f, 0.f, 0.f, 0.f};
            #pragma unroll 8
            for (int tf = 0; tf < TF; ++tf) {
                f32x4 xv = __builtin_nontemporal_load(xp + (size_t)tf * strideV);
                f32x4 wv = wp[(size_t)tf * strideV];
                a += xv * wv;
            }
            int4 gi = *(const int4*)(gene_ids + t);
            float* base = acc + (size_t)b * G;
            float v = a.x; int cgid = gi.x;
            if (gi.y == cgid) v += a.y; else { atomicAdd(base + cgid, v); cgid = gi.y; v = a.y; }
            if (gi.z == cgid) v += a.z; else { atomicAdd(base + cgid, v); cgid = gi.z; v = a.z; }
            if (gi.w == cgid) v += a.w; else { atomicAdd(base + cgid, v); cgid = gi.w; v = a.w; }
            atomicAdd(base + cgid, v);
        }
    }
    gg.sync();

    // ---- P2: x_cat = relu(acc + b_sub) ; degree histogram over dst ----
    for (int i = tid; i < BG; i += nth) {
        int g = i % G;
        float v = acc[i] + b_sub[g];
        out_xcat[i] = v > 0.f ? v : 0.f;
    }
    for (int e = tid; e < E2; e += nth) atomicAdd(&deg[ei[E2 + e]], 1.0f);
    gg.sync();

    // ---- P3: s[b,dst] += xcat[b,src] * dinv[src]*dinv[dst] ----
    {
        const int etot = B * E2;
        for (int idx = tid; idx < etot; idx += nth) {
            int b = idx / E2;
            int e = idx - b * E2;
            int src = ei[e], dst = ei[E2 + e];
            float ds = deg[src], dd = deg[dst];
            float ns = (ds > 0.f) ? (1.0f / sqrtf(fmaxf(ds, 1.0f))) : 0.f;
            float nd = (dd > 0.f) ? (1.0f / sqrtf(fmaxf(dd, 1.0f))) : 0.f;
            atomicAdd(&s[(size_t)b * G + dst], out_xcat[(size_t)b * G + src] * (ns * nd));
        }
    }
    gg.sync();

    // ---- P4: g = relu(w_conv*s + b_conv); out += g @ w_out (wave-reduce) ----
    {
        const float wc0 = w_conv[0], wc1 = w_conv[1];
        const float bc0 = b_conv[0], bc1 = b_conv[1];
        const int wid = tid >> 6, lane = tid & 63;
        const int WPB = (G + 63) >> 6;          // waves per batch row
        if (wid < B * WPB) {
            int b = wid / WPB;
            int n = (wid - b * WPB) * 64 + lane;
            float a0 = 0.f, a1 = 0.f, a2 = 0.f;
            if (n < G) {
                size_t i = (size_t)b * G + n;
                float sv = s[i];
                float g0 = fmaxf(sv * wc0 + bc0, 0.f);
                float g1 = fmaxf(sv * wc1 + bc1, 0.f);
                out_g[2 * i + 0] = g0;          // b*2G + 2n + f == 2*i + f
                out_g[2 * i + 1] = g1;
                const float* w0 = w_out + (size_t)6 * n;   // rows 2n, 2n+1 of [2G,3]
                a0 = g0 * w0[0] + g1 * w0[3];
                a1 = g0 * w0[1] + g1 * w0[4];
                a2 = g0 * w0[2] + g1 * w0[5];
            }
            for (int off = 32; off > 0; off >>= 1) {
                a0 += __shfl_down(a0, off);
                a1 += __shfl_down(a1, off);
                a2 += __shfl_down(a2, off);
            }
            if (lane == 0) {
                atomicAdd(&out_fin[b * 3 + 0], a0);
                atomicAdd(&out_fin[b * 3 + 1], a1);
                atomicAdd(&out_fin[b * 3 + 2], a2);
            }
        }
    }
}

// ==================== Fallback path (proven R1 kernels) ====================
__global__ void k_subnet(const float* __restrict__ x, const float* __restrict__ w_sub,
                         const int* __restrict__ gene_ids, float* __restrict__ acc,
                         int TF, int T, int G) {
    int t = (blockIdx.x * blockDim.x + threadIdx.x) * 4;
    int b = blockIdx.y;
    if (t >= T) return;
    const size_t xbase = (size_t)b * TF * T;
    if (t + 3 < T && (T % 4) == 0) {
        const f32x4* xp = (const f32x4*)(x + xbase + t);
        const f32x4* wp = (const f32x4*)(w_sub + t);
        const size_t strideV = (size_t)T / 4;
        f32x4 a = {0.f, 0.f, 0.f, 0.f};
        #pragma unroll 8
        for (int tf = 0; tf < TF; ++tf) {
            f32x4 xv = __builtin_nontemporal_load(xp + (size_t)tf * strideV);
            f32x4 wv = wp[(size_t)tf * strideV];
            a += xv * wv;
        }
        int4 gi = *(const int4*)(gene_ids + t);
        float* base = acc + (size_t)b * G;
        float v = a.x; int cgid = gi.x;
        if (gi.y == cgid) v += a.y; else { atomicAdd(base + cgid, v); cgid = gi.y; v = a.y; }
        if (gi.z == cgid) v += a.z; else { atomicAdd(base + cgid, v); cgid = gi.z; v = a.z; }
        if (gi.w == cgid) v += a.w; else { atomicAdd(base + cgid, v); cgid = gi.w; v = a.w; }
        atomicAdd(base + cgid, v);
    } else {
        for (int tt = t; tt < T && tt < t + 4; ++tt) {
            float a = 0.f;
            for (int tf = 0; tf < TF; ++tf)
                a += x[xbase + (size_t)tf * T + tt] * w_sub[(size_t)tf * T + tt];
            atomicAdd(acc + (size_t)b * G + gene_ids[tt], a);
        }
    }
}

__global__ void k_xcatdeg(const float* __restrict__ acc, const float* __restrict__ b_sub,
                          float* __restrict__ xcat,
                          const int* __restrict__ ei, float* __restrict__ deg,
                          const float* __restrict__ b_out, float* __restrict__ out_fin,
                          int BG, int G, int E2, int B3) {
    int i = blockIdx.x * blockDim.x + threadIdx.x;
    if (i < BG) {
        int g = i % G;
        float v = acc[i] + b_sub[g];
        xcat[i] = v > 0.f ? v : 0.f;
    }
    if (i < E2) atomicAdd(&deg[ei[E2 + i]], 1.0f);
    if (i < B3) out_fin[i] = b_out[i % 3];
}

__global__ void k_scatter(const float* __restrict__ xcat, const int* __restrict__ ei,
                          const float* __restrict__ deg, float* __restrict__ s,
                          int G, int E2) {
    int e = blockIdx.x * blockDim.x + threadIdx.x;
    if (e >= E2) return;
    int b = blockIdx.y;
    int src = ei[e], dst = ei[E2 + e];
    float ds = deg[src], dd = deg[dst];
    float ns = (ds > 0.f) ? (1.0f / sqrtf(fmaxf(ds, 1.0f))) : 0.f;
    float nd = (dd > 0.f) ? (1.0f / sqrtf(fmaxf(dd, 1.0f))) : 0.f;
    atomicAdd(&s[(size_t)b * G + dst], xcat[(size_t)b * G + src] * (ns * nd));
}

__global__ void k_gfinout(const float* __restrict__ s, const float* __restrict__ w_conv,
                          const float* __restrict__ b_conv, const float* __restrict__ w_out,
                          float* __restrict__ gout, float* __restrict__ out_fin, int G) {
    int n = blockIdx.x * blockDim.x + threadIdx.x;
    int b = blockIdx.y;
    float a0 = 0.f, a1 = 0.f, a2 = 0.f;
    if (n < G) {
        size_t i = (size_t)b * G + n;
        float sv = s[i];
        float g0 = sv * w_conv[0] + b_conv[0]; g0 = g0 > 0.f ? g0 : 0.f;
        float g1 = sv * w_conv[1] + b_conv[1]; g1 = g1 > 0.f ? g1 : 0.f;
        gout[2 * i + 0] = g0;
        gout[2 * i + 1] = g1;
        const float* w0 = w_out + (size_t)6 * n;
        a0 = g0 * w0[0] + g1 * w0[3];
        a1 = g0 * w0[1] + g1 * w0[4];
        a2 = g0 * w0[2] + g1 * w0[5];
    }
    for (int off = 32; off > 0; off >>= 1) {
        a0 += __shfl_down(a0, off);
        a1 += __shfl_down(a1, off);
        a2 += __shfl_down(a2, off);
    }
    __shared__ float red[3][4];
    int lane = threadIdx.x & 63;
    int wid  = threadIdx.x >> 6;
    if (lane == 0) { red[0][wid] = a0; red[1][wid] = a1; red[2][wid] = a2; }
    __syncthreads();
    if (threadIdx.x == 0) {
        atomicAdd(&out_fin[b * 3 + 0], red[0][0] + red[0][1] + red[0][2] + red[0][3]);
        atomicAdd(&out_fin[b * 3 + 1], red[1][0] + red[1][1] + red[1][2] + red[1][3]);
        atomicAdd(&out_fin[b * 3 + 2], red[2][0] + red[2][1] + red[2][2] + red[2][3]);
    }
}

extern "C" void kernel_launch(void* const* d_in, const int* in_sizes, int n_in,
                              void* d_out, int out_size, void* d_ws, size_t ws_size,
                              hipStream_t stream) {
    const float* x        = (const float*)d_in[0];
    const int*   gene_ids = (const int*)d_in[1];
    const float* w_sub    = (const float*)d_in[2];
    const float* b_sub    = (const float*)d_in[3];
    const int*   ei       = (const int*)d_in[4];
    const float* w_conv   = (const float*)d_in[5];
    const float* b_conv   = (const float*)d_in[6];
    const float* w_out    = (const float*)d_in[7];
    const float* b_out    = (const float*)d_in[8];

    int G  = in_sizes[3];
    int T  = in_sizes[1];
    int TF = in_sizes[2] / T;
    int B  = in_sizes[0] / (TF * T);
    int E2 = in_sizes[4] / 2;     // 2E
    const int BG = B * G;

    // workspace layout (floats): acc[BG] | deg[G] | s[BG]
    float* acc = (float*)d_ws;
    float* deg = acc + BG;
    float* s   = deg + G;

    float* out_xcat = (float*)d_out;            // [B, G]
    float* out_g    = out_xcat + BG;            // [B, 2G]
    float* out_fin  = out_g + (size_t)2 * BG;   // [B, 3]

    // ---- one cooperative launch: 1024 blocks x 256 = exactly 4 blocks/CU ----
    void* args[] = {
        (void*)&x, (void*)&gene_ids, (void*)&w_sub, (void*)&b_sub, (void*)&ei,
        (void*)&w_conv, (void*)&b_conv, (void*)&w_out, (void*)&b_out,
        (void*)&acc, (void*)&deg, (void*)&s,
        (void*)&out_xcat, (void*)&out_g, (void*)&out_fin,
        (void*)&B, (void*)&TF, (void*)&T, (void*)&G, (void*)&E2
    };
    hipError_t err = hipLaunchCooperativeKernel((const void*)k_mega, dim3(1024), dim3(256),
                                                args, 0, stream);
    if (err == hipSuccess) return;

    // ---- fallback: proven R1 multi-dispatch path ----
    hipMemsetAsync(d_ws, 0, (size_t)(BG + G + BG) * sizeof(float), stream);
    {
        int tthreads = (T + 3) / 4;
        dim3 grid((tthreads + 255) / 256, B);
        k_subnet<<<grid, 256, 0, stream>>>(x, w_sub, gene_ids, acc, TF, T, G);
    }
    {
        int mx = BG > E2 ? BG : E2;
        int b3 = B * 3;
        if (mx < b3) mx = b3;
        k_xcatdeg<<<(mx + 255) / 256, 256, 0, stream>>>(acc, b_sub, out_xcat, ei, deg,
                                                        b_out, out_fin, BG, G, E2, b3);
    }
    {
        dim3 grid((E2 + 255) / 256, B);
        k_scatter<<<grid, 256, 0, stream>>>(out_xcat, ei, deg, s, G, E2);
    }
    {
        dim3 grid((G + 255) / 256, B);
        k_gfinout<<<grid, 256, 0, stream>>>(s, w_conv, b_conv, w_out, out_g, out_fin, G);
    }
}

// Round 3
// 742.316 us; speedup vs baseline: 1.5104x; 1.5104x over previous
//
#include <hip/hip_runtime.h>

// Problem constants derived at launch from in_sizes:
// in[0]=x [B,TF,T], in[1]=gene_ids [T], in[2]=w_sub [TF,T], in[3]=b_sub [G],
// in[4]=edge_index [2,2E], in[5]=w_conv [1,2], in[6]=b_conv [2],
// in[7]=w_out [2G,3], in[8]=b_out [3]
// d_out = x_cat [B,G] ++ g [B,2G] ++ out [B,3]  (float32)

typedef float f32x4 __attribute__((ext_vector_type(4)));

// ---------------- Stage 1: per-gene subnet dot + segment scatter ----------------
// z[b,t] = sum_tf x[b,tf,t]*w_sub[tf,t];  acc[b, gene_ids[t]] += z[b,t]
// 8 columns (2 f32x4) per thread, dual accumulators: 4 loads/tf-iter, unroll 4
// -> ~16 loads (~8 KB) in flight per wave. x streamed once -> non-temporal loads
// keep w_sub (32x reuse) resident in L2/L3. NO __launch_bounds__: R2 showed a
// forced 4-waves/EU budget starves VGPRs (32) and collapses MLP to ~1 load/CU.
__global__ void k_subnet(const float* __restrict__ x, const float* __restrict__ w_sub,
                         const int* __restrict__ gene_ids, float* __restrict__ acc,
                         int TF, int T, int G) {
    int t = (blockIdx.x * blockDim.x + threadIdx.x) * 8;
    int b = blockIdx.y;
    if (t >= T) return;
    const size_t xbase = (size_t)b * TF * T;
    if (t + 7 < T && (T % 8) == 0) {
        const f32x4* xp = (const f32x4*)(x + xbase + t);
        const f32x4* wp = (const f32x4*)(w_sub + t);
        const size_t strideV = (size_t)T / 4;      // row stride in f32x4 units
        f32x4 a0 = {0.f, 0.f, 0.f, 0.f};
        f32x4 a1 = {0.f, 0.f, 0.f, 0.f};
        #pragma unroll 4
        for (int tf = 0; tf < TF; ++tf) {
            const size_t o = (size_t)tf * strideV;
            f32x4 xv0 = __builtin_nontemporal_load(xp + o);
            f32x4 xv1 = __builtin_nontemporal_load(xp + o + 1);
            f32x4 wv0 = wp[o];
            f32x4 wv1 = wp[o + 1];
            a0 += xv0 * wv0;
            a1 += xv1 * wv1;
        }
        int4 gA = *(const int4*)(gene_ids + t);
        int4 gB = *(const int4*)(gene_ids + t + 4);
        float vals[8] = {a0.x, a0.y, a0.z, a0.w, a1.x, a1.y, a1.z, a1.w};
        int   gs[8]   = {gA.x, gA.y, gA.z, gA.w, gB.x, gB.y, gB.z, gB.w};
        float* base = acc + (size_t)b * G;
        // merge adjacent columns belonging to the same gene before atomics
        float v = vals[0]; int cg = gs[0];
        #pragma unroll
        for (int k = 1; k < 8; ++k) {
            if (gs[k] == cg) v += vals[k];
            else { atomicAdd(base + cg, v); cg = gs[k]; v = vals[k]; }
        }
        atomicAdd(base + cg, v);
    } else {
        // scalar tail (not taken for T % 8 == 0, kept for generality)
        for (int tt = t; tt < T && tt < t + 8; ++tt) {
            float a = 0.f;
            for (int tf = 0; tf < TF; ++tf)
                a += x[xbase + (size_t)tf * T + tt] * w_sub[(size_t)tf * T + tt];
            atomicAdd(acc + (size_t)b * G + gene_ids[tt], a);
        }
    }
}

// ---------------- Stage 2 (fused): x_cat = relu(acc+b_sub), deg count, out init ----
__global__ void k_xcatdeg(const float* __restrict__ acc, const float* __restrict__ b_sub,
                          float* __restrict__ xcat,
                          const int* __restrict__ ei, float* __restrict__ deg,
                          const float* __restrict__ b_out, float* __restrict__ out_fin,
                          int BG, int G, int E2, int B3) {
    int i = blockIdx.x * blockDim.x + threadIdx.x;
    if (i < BG) {
        int g = i % G;
        float v = acc[i] + b_sub[g];
        xcat[i] = v > 0.f ? v : 0.f;
    }
    if (i < E2) atomicAdd(&deg[ei[E2 + i]], 1.0f);
    if (i < B3) out_fin[i] = b_out[i % 3];   // bias-init so stage 4 can atomicAdd
}

// ---------------- Stage 3 (fused norm): s[b,dst] += xcat[b,src]*dinv[src]*dinv[dst] --
__global__ void k_scatter(const float* __restrict__ xcat, const int* __restrict__ ei,
                          const float* __restrict__ deg, float* __restrict__ s,
                          int G, int E2) {
    int e = blockIdx.x * blockDim.x + threadIdx.x;
    if (e >= E2) return;
    int b = blockIdx.y;
    int src = ei[e], dst = ei[E2 + e];
    float ds = deg[src], dd = deg[dst];
    float ns = (ds > 0.f) ? (1.0f / sqrtf(fmaxf(ds, 1.0f))) : 0.f;
    float nd = (dd > 0.f) ? (1.0f / sqrtf(fmaxf(dd, 1.0f))) : 0.f;
    atomicAdd(&s[(size_t)b * G + dst], xcat[(size_t)b * G + src] * (ns * nd));
}

// ---------------- Stage 4 (fused): g = relu(w_conv*s+b_conv)  AND  out = g@w_out+b_out
__global__ void k_gfinout(const float* __restrict__ s, const float* __restrict__ w_conv,
                          const float* __restrict__ b_conv, const float* __restrict__ w_out,
                          float* __restrict__ gout, float* __restrict__ out_fin, int G) {
    int n = blockIdx.x * blockDim.x + threadIdx.x;
    int b = blockIdx.y;
    float a0 = 0.f, a1 = 0.f, a2 = 0.f;
    if (n < G) {
        size_t i = (size_t)b * G + n;
        float sv = s[i];
        float g0 = sv * w_conv[0] + b_conv[0]; g0 = g0 > 0.f ? g0 : 0.f;
        float g1 = sv * w_conv[1] + b_conv[1]; g1 = g1 > 0.f ? g1 : 0.f;
        gout[2 * i + 0] = g0;                 // b*2G + 2n + f == 2*i + f
        gout[2 * i + 1] = g1;
        const float* w0 = w_out + (size_t)6 * n;  // rows 2n and 2n+1 of [2G,3]
        a0 = g0 * w0[0] + g1 * w0[3];
        a1 = g0 * w0[1] + g1 * w0[4];
        a2 = g0 * w0[2] + g1 * w0[5];
    }
    // 64-lane wave reduce, then cross-wave via LDS
    for (int off = 32; off > 0; off >>= 1) {
        a0 += __shfl_down(a0, off);
        a1 += __shfl_down(a1, off);
        a2 += __shfl_down(a2, off);
    }
    __shared__ float red[3][4];
    int lane = threadIdx.x & 63;
    int wid  = threadIdx.x >> 6;
    if (lane == 0) { red[0][wid] = a0; red[1][wid] = a1; red[2][wid] = a2; }
    __syncthreads();
    if (threadIdx.x == 0) {
        atomicAdd(&out_fin[b * 3 + 0], red[0][0] + red[0][1] + red[0][2] + red[0][3]);
        atomicAdd(&out_fin[b * 3 + 1], red[1][0] + red[1][1] + red[1][2] + red[1][3]);
        atomicAdd(&out_fin[b * 3 + 2], red[2][0] + red[2][1] + red[2][2] + red[2][3]);
    }
}

extern "C" void kernel_launch(void* const* d_in, const int* in_sizes, int n_in,
                              void* d_out, int out_size, void* d_ws, size_t ws_size,
                              hipStream_t stream) {
    const float* x        = (const float*)d_in[0];
    const int*   gene_ids = (const int*)d_in[1];
    const float* w_sub    = (const float*)d_in[2];
    const float* b_sub    = (const float*)d_in[3];
    const int*   ei       = (const int*)d_in[4];
    const float* w_conv   = (const float*)d_in[5];
    const float* b_conv   = (const float*)d_in[6];
    const float* w_out    = (const float*)d_in[7];
    const float* b_out    = (const float*)d_in[8];

    const int G  = in_sizes[3];
    const int T  = in_sizes[1];
    const int TF = in_sizes[2] / T;
    const int B  = in_sizes[0] / (TF * T);
    const int E2 = in_sizes[4] / 2;     // 2E
    const int BG = B * G;

    // workspace layout (floats): acc[BG] | deg[G] | s[BG]
    float* acc = (float*)d_ws;
    float* deg = acc + BG;
    float* s   = deg + G;
    hipMemsetAsync(d_ws, 0, (size_t)(BG + G + BG) * sizeof(float), stream);

    float* out_xcat = (float*)d_out;            // [B, G]
    float* out_g    = out_xcat + BG;            // [B, 2G]
    float* out_fin  = out_g + (size_t)2 * BG;   // [B, 3]

    // Stage 1 (8 columns per thread)
    {
        int tthreads = (T + 7) / 8;
        dim3 grid((tthreads + 255) / 256, B);
        k_subnet<<<grid, 256, 0, stream>>>(x, w_sub, gene_ids, acc, TF, T, G);
    }
    // Stage 2 (xcat + deg + out-bias-init)
    {
        int mx = BG > E2 ? BG : E2;
        int b3 = B * 3;
        if (mx < b3) mx = b3;
        k_xcatdeg<<<(mx + 255) / 256, 256, 0, stream>>>(acc, b_sub, out_xcat, ei, deg,
                                                        b_out, out_fin, BG, G, E2, b3);
    }
    // Stage 3 (scatter with on-the-fly GCN norm)
    {
        dim3 grid((E2 + 255) / 256, B);
        k_scatter<<<grid, 256, 0, stream>>>(out_xcat, ei, deg, s, G, E2);
    }
    // Stage 4 (g + final out, fused)
    {
        dim3 grid((G + 255) / 256, B);
        k_gfinout<<<grid, 256, 0, stream>>>(s, w_conv, b_conv, w_out, out_g, out_fin, G);
    }
}

// Round 4
// 726.199 us; speedup vs baseline: 1.5439x; 1.0222x over previous
//
#include <hip/hip_runtime.h>

// Problem constants derived at launch from in_sizes:
// in[0]=x [B,TF,T], in[1]=gene_ids [T], in[2]=w_sub [TF,T], in[3]=b_sub [G],
// in[4]=edge_index [2,2E], in[5]=w_conv [1,2], in[6]=b_conv [2],
// in[7]=w_out [2G,3], in[8]=b_out [3]
// d_out = x_cat [B,G] ++ g [B,2G] ++ out [B,3]  (float32)

typedef float f32x4 __attribute__((ext_vector_type(4)));

// ---------------- Stage 1: per-gene subnet dot + segment scatter ----------------
// Inner loop EXACTLY the proven R1 4-wide form (16B fully-coalesced lane loads;
// R3 showed 2-quad-per-lane interleaving halves transaction efficiency: +19us).
// NEW: XCD-aware job remap. Grid is 1-D (NCHUNK*B blocks); with bid%8 -> XCD
// round-robin, giving XCD k the contiguous job range [k*per, (k+1)*per) makes
// each XCD own ~6.75 t-chunks for ALL b: per-XCD w_sub working set ~1.7MB < 4MB
// L2, so the 32x re-read of w_sub hits L2 instead of L3 (removes ~434MB of L3
// traffic competing with the x HBM stream). Index-only change.
__global__ void k_subnet(const float* __restrict__ x, const float* __restrict__ w_sub,
                         const int* __restrict__ gene_ids, float* __restrict__ acc,
                         int TF, int T, int G, int B) {
    int bid = blockIdx.x;
    int nb  = gridDim.x;                 // NCHUNK * B
    int job;
    if ((nb & 7) == 0) {                 // bijective XCD swizzle (8 XCDs)
        int per = nb >> 3;
        job = (bid & 7) * per + (bid >> 3);
    } else {
        job = bid;
    }
    int tchunk = job / B;                // b fastest within a t-chunk
    int b      = job - tchunk * B;
    int t = (tchunk * blockDim.x + (int)threadIdx.x) * 4;
    if (t >= T) return;
    const size_t xbase = (size_t)b * TF * T;
    if (t + 3 < T && (T % 4) == 0) {
        const f32x4* xp = (const f32x4*)(x + xbase + t);
        const f32x4* wp = (const f32x4*)(w_sub + t);
        const size_t strideV = (size_t)T / 4;
        f32x4 a = {0.f, 0.f, 0.f, 0.f};
        #pragma unroll 8
        for (int tf = 0; tf < TF; ++tf) {
            f32x4 xv = __builtin_nontemporal_load(xp + (size_t)tf * strideV);
            f32x4 wv = wp[(size_t)tf * strideV];
            a += xv * wv;
        }
        int4 gi = *(const int4*)(gene_ids + t);
        float* base = acc + (size_t)b * G;
        // merge adjacent columns belonging to the same gene before atomics
        float v = a.x; int cg = gi.x;
        if (gi.y == cg) v += a.y; else { atomicAdd(base + cg, v); cg = gi.y; v = a.y; }
        if (gi.z == cg) v += a.z; else { atomicAdd(base + cg, v); cg = gi.z; v = a.z; }
        if (gi.w == cg) v += a.w; else { atomicAdd(base + cg, v); cg = gi.w; v = a.w; }
        atomicAdd(base + cg, v);
    } else {
        // scalar tail (not taken for T % 4 == 0, kept for generality)
        for (int tt = t; tt < T && tt < t + 4; ++tt) {
            float a = 0.f;
            for (int tf = 0; tf < TF; ++tf)
                a += x[xbase + (size_t)tf * T + tt] * w_sub[(size_t)tf * T + tt];
            atomicAdd(acc + (size_t)b * G + gene_ids[tt], a);
        }
    }
}

// ---------------- Stage 2 (fused): x_cat = relu(acc+b_sub), deg count, out init ----
__global__ void k_xcatdeg(const float* __restrict__ acc, const float* __restrict__ b_sub,
                          float* __restrict__ xcat,
                          const int* __restrict__ ei, float* __restrict__ deg,
                          const float* __restrict__ b_out, float* __restrict__ out_fin,
                          int BG, int G, int E2, int B3) {
    int i = blockIdx.x * blockDim.x + threadIdx.x;
    if (i < BG) {
        int g = i % G;
        float v = acc[i] + b_sub[g];
        xcat[i] = v > 0.f ? v : 0.f;
    }
    if (i < E2) atomicAdd(&deg[ei[E2 + i]], 1.0f);
    if (i < B3) out_fin[i] = b_out[i % 3];   // bias-init so stage 4 can atomicAdd
}

// ---------------- Stage 3: one thread per edge, loop over batch ----------------
// Loads ei/deg/norm ONCE per edge (was 32x). xcat gathers are L2-resident
// (256KB working set). No-return atomicAdd is fire-and-forget -> the b-loop
// pipelines fully; total atomic count unchanged.
__global__ void k_scatter(const float* __restrict__ xcat, const int* __restrict__ ei,
                          const float* __restrict__ deg, float* __restrict__ s,
                          int G, int E2, int B) {
    int e = blockIdx.x * blockDim.x + threadIdx.x;
    if (e >= E2) return;
    int src = ei[e], dst = ei[E2 + e];
    float ds = deg[src], dd = deg[dst];
    float ns = (ds > 0.f) ? (1.0f / sqrtf(fmaxf(ds, 1.0f))) : 0.f;
    float nd = (dd > 0.f) ? (1.0f / sqrtf(fmaxf(dd, 1.0f))) : 0.f;
    float norm = ns * nd;
    #pragma unroll 8
    for (int b = 0; b < B; ++b) {
        atomicAdd(&s[(size_t)b * G + dst], xcat[(size_t)b * G + src] * norm);
    }
}

// ---------------- Stage 4 (fused): g = relu(w_conv*s+b_conv)  AND  out = g@w_out+b_out
__global__ void k_gfinout(const float* __restrict__ s, const float* __restrict__ w_conv,
                          const float* __restrict__ b_conv, const float* __restrict__ w_out,
                          float* __restrict__ gout, float* __restrict__ out_fin, int G) {
    int n = blockIdx.x * blockDim.x + threadIdx.x;
    int b = blockIdx.y;
    float a0 = 0.f, a1 = 0.f, a2 = 0.f;
    if (n < G) {
        size_t i = (size_t)b * G + n;
        float sv = s[i];
        float g0 = sv * w_conv[0] + b_conv[0]; g0 = g0 > 0.f ? g0 : 0.f;
        float g1 = sv * w_conv[1] + b_conv[1]; g1 = g1 > 0.f ? g1 : 0.f;
        gout[2 * i + 0] = g0;                 // b*2G + 2n + f == 2*i + f
        gout[2 * i + 1] = g1;
        const float* w0 = w_out + (size_t)6 * n;  // rows 2n and 2n+1 of [2G,3]
        a0 = g0 * w0[0] + g1 * w0[3];
        a1 = g0 * w0[1] + g1 * w0[4];
        a2 = g0 * w0[2] + g1 * w0[5];
    }
    // 64-lane wave reduce, then cross-wave via LDS
    for (int off = 32; off > 0; off >>= 1) {
        a0 += __shfl_down(a0, off);
        a1 += __shfl_down(a1, off);
        a2 += __shfl_down(a2, off);
    }
    __shared__ float red[3][4];
    int lane = threadIdx.x & 63;
    int wid  = threadIdx.x >> 6;
    if (lane == 0) { red[0][wid] = a0; red[1][wid] = a1; red[2][wid] = a2; }
    __syncthreads();
    if (threadIdx.x == 0) {
        atomicAdd(&out_fin[b * 3 + 0], red[0][0] + red[0][1] + red[0][2] + red[0][3]);
        atomicAdd(&out_fin[b * 3 + 1], red[1][0] + red[1][1] + red[1][2] + red[1][3]);
        atomicAdd(&out_fin[b * 3 + 2], red[2][0] + red[2][1] + red[2][2] + red[2][3]);
    }
}

extern "C" void kernel_launch(void* const* d_in, const int* in_sizes, int n_in,
                              void* d_out, int out_size, void* d_ws, size_t ws_size,
                              hipStream_t stream) {
    const float* x        = (const float*)d_in[0];
    const int*   gene_ids = (const int*)d_in[1];
    const float* w_sub    = (const float*)d_in[2];
    const float* b_sub    = (const float*)d_in[3];
    const int*   ei       = (const int*)d_in[4];
    const float* w_conv   = (const float*)d_in[5];
    const float* b_conv   = (const float*)d_in[6];
    const float* w_out    = (const float*)d_in[7];
    const float* b_out    = (const float*)d_in[8];

    const int G  = in_sizes[3];
    const int T  = in_sizes[1];
    const int TF = in_sizes[2] / T;
    const int B  = in_sizes[0] / (TF * T);
    const int E2 = in_sizes[4] / 2;     // 2E
    const int BG = B * G;

    // workspace layout (floats): acc[BG] | deg/dinv[G] | s[BG]
    float* acc = (float*)d_ws;
    float* deg = acc + BG;
    float* s   = deg + G;
    hipMemsetAsync(d_ws, 0, (size_t)(BG + G + BG) * sizeof(float), stream);

    float* out_xcat = (float*)d_out;            // [B, G]
    float* out_g    = out_xcat + BG;            // [B, 2G]
    float* out_fin  = out_g + (size_t)2 * BG;   // [B, 3]

    // Stage 1 (4 floats per thread, 1-D grid with XCD-aware job remap)
    {
        int tthreads = (T + 3) / 4;
        int nchunk   = (tthreads + 255) / 256;      // 54
        k_subnet<<<nchunk * B, 256, 0, stream>>>(x, w_sub, gene_ids, acc, TF, T, G, B);
    }
    // Stage 2 (xcat + deg + out-bias-init)
    {
        int mx = BG > E2 ? BG : E2;
        int b3 = B * 3;
        if (mx < b3) mx = b3;
        k_xcatdeg<<<(mx + 255) / 256, 256, 0, stream>>>(acc, b_sub, out_xcat, ei, deg,
                                                        b_out, out_fin, BG, G, E2, b3);
    }
    // Stage 3 (per-edge thread, b-loop, on-the-fly GCN norm)
    k_scatter<<<(E2 + 255) / 256, 256, 0, stream>>>(out_xcat, ei, deg, s, G, E2, B);
    // Stage 4 (g + final out, fused)
    {
        dim3 grid((G + 255) / 256, B);
        k_gfinout<<<grid, 256, 0, stream>>>(s, w_conv, b_conv, w_out, out_g, out_fin, G);
    }
}